// Round 10
// baseline (1480.992 us; speedup 1.0000x reference)
//
#include <hip/hip_runtime.h>

// GNN encoder + GRU decoder. R10: ONE kernel per step (29 launches total).
// R9 post-mortem: all kernels <15us, 770us / 56 launches = launch-count bound.
// Fusion insight: block (b,r) computes msg row r in-LDS; the GRU / node-MLP
// update for row r needs only msg[r], h[r], dec[r] -- block-local. So the
// step kernel = edge (R9's validated MFMA body) + row-wise VALU tail
// (dot2-based). No g_msg global round-trip; h ping-pongs via g_hbuf.
// 512 blocks x 256 thr, ~29KB LDS, 2 blocks/CU (R9's proven-fast config).

#define TSTEPS 25

typedef _Float16 half_t;
typedef __attribute__((ext_vector_type(8))) _Float16 half8;
typedef __attribute__((ext_vector_type(2))) _Float16 half2v;
typedef __attribute__((ext_vector_type(8))) short short8;
typedef __attribute__((ext_vector_type(4))) float f32x4;

#define OFF_ENC_W1T 0          // [256 j][160 k]
#define OFF_ENC_W2T 40960      // [128 j][256 k]
#define OFF_PE_W1T  73728      // [512 j][128 k]  (j<256: P, j>=256: Q)
#define OFF_PE_W2T  139264     // [128 j][256 k]
#define OFF_PN_W1T  172032     // [256 j][128 k]
#define OFF_PN_W2T  204800     // [128 j][256 k]
#define OFF_DE_W1T  237568     // [512 j][128 k]
#define OFF_DE_W2T  303104     // [128 j][256 k]
#define OFF_WGT     335872     // [512 c][288 k]: c-groups {rs,is,ns,hn} x 128
#define WTOTAL      483328

__device__ __align__(16) half_t g_wf16[WTOTAL];
__device__ __align__(16) float g_hbuf[2 * 512 * 128];   // ping-pong h

__device__ __forceinline__ half8 h8zero() {
    half8 z;
    #pragma unroll
    for (int e = 0; e < 8; ++e) z[e] = (half_t)0.f;
    return z;
}
__device__ __forceinline__ half8 relu8(half8 x) {
    short8 s = *(short8*)&x;
    short8 m = s >> 15;
    s = s & ~m;
    return *(half8*)&s;
}
__device__ __forceinline__ float dot8(half8 a, half8 w, float acc) {
#if __has_builtin(__builtin_amdgcn_fdot2)
    const half2v* ap = (const half2v*)&a;
    const half2v* wp = (const half2v*)&w;
    acc = __builtin_amdgcn_fdot2(ap[0], wp[0], acc, false);
    acc = __builtin_amdgcn_fdot2(ap[1], wp[1], acc, false);
    acc = __builtin_amdgcn_fdot2(ap[2], wp[2], acc, false);
    acc = __builtin_amdgcn_fdot2(ap[3], wp[3], acc, false);
#else
    #pragma unroll
    for (int e = 0; e < 8; ++e) acc += (float)a[e] * (float)w[e];
#endif
    return acc;
}
#define MFMA(a, b, c) __builtin_amdgcn_mfma_f32_16x16x32_f16((a), (b), (c), 0, 0, 0)

// ---------------- weight conversion (once per call; R7/R8-validated) --------
__global__ void convert_kernel(const float* __restrict__ enc_w1, const float* __restrict__ enc_w2,
                               const float* __restrict__ pe_w1, const float* __restrict__ pe_w2,
                               const float* __restrict__ pn_w1, const float* __restrict__ pn_w2,
                               const float* __restrict__ de_w1, const float* __restrict__ de_w2,
                               const float* __restrict__ w_hr, const float* __restrict__ w_hi,
                               const float* __restrict__ w_hn, const float* __restrict__ w_ir,
                               const float* __restrict__ w_ii, const float* __restrict__ w_in) {
    const int idx = blockIdx.x * 256 + threadIdx.x;
    if (idx >= WTOTAL) return;
    float v = 0.f;
    if (idx < OFF_ENC_W2T) {
        int o = idx, j = o / 160, k = o - j * 160;
        v = (k < 150) ? enc_w1[k * 256 + j] : 0.f;
    } else if (idx < OFF_PE_W1T) {
        int o = idx - OFF_ENC_W2T, j = o >> 8, k = o & 255;
        v = enc_w2[k * 128 + j];
    } else if (idx < OFF_PE_W2T) {
        int o = idx - OFF_PE_W1T, j = o >> 7, k = o & 127;
        v = pe_w1[(k + ((j >= 256) ? 128 : 0)) * 256 + (j & 255)];
    } else if (idx < OFF_PN_W1T) {
        int o = idx - OFF_PE_W2T, j = o >> 8, k = o & 255;
        v = pe_w2[k * 128 + j];
    } else if (idx < OFF_PN_W2T) {
        int o = idx - OFF_PN_W1T, j = o >> 7, k = o & 127;
        v = pn_w1[k * 256 + j];
    } else if (idx < OFF_DE_W1T) {
        int o = idx - OFF_PN_W2T, j = o >> 8, k = o & 255;
        v = pn_w2[k * 128 + j];
    } else if (idx < OFF_DE_W2T) {
        int o = idx - OFF_DE_W1T, j = o >> 7, k = o & 127;
        v = de_w1[(k + ((j >= 256) ? 128 : 0)) * 256 + (j & 255)];
    } else if (idx < OFF_WGT) {
        int o = idx - OFF_DE_W2T, j = o >> 8, k = o & 255;
        v = de_w2[k * 128 + j];
    } else {
        int o = idx - OFF_WGT, j = o / 288, k = o - j * 288;
        int g = j >> 7, jj = j & 127;
        if (g == 0)
            v = (k < 128) ? w_ir[k * 128 + jj] : (k < 256) ? w_hr[(k - 128) * 128 + jj]
              : (k < 259) ? w_ir[(128 + k - 256) * 128 + jj] : 0.f;
        else if (g == 1)
            v = (k < 128) ? w_ii[k * 128 + jj] : (k < 256) ? w_hi[(k - 128) * 128 + jj]
              : (k < 259) ? w_ii[(128 + k - 256) * 128 + jj] : 0.f;
        else if (g == 2)
            v = (k < 128) ? w_in[k * 128 + jj]
              : (k >= 256 && k < 259) ? w_in[(128 + k - 256) * 128 + jj] : 0.f;
        else
            v = (k >= 128 && k < 256) ? w_hn[(k - 128) * 128 + jj] : 0.f;
    }
    g_wf16[idx] = (half_t)v;
}

// ---------------- encoder MLP (grid 128; R9-validated) ----------------------
__global__ void __launch_bounds__(512, 2)
encoder_kernel(const float* __restrict__ enc_in,
               const float* __restrict__ enc_b1, const float* __restrict__ enc_b2) {
    const int b = blockIdx.x & 15;
    const int sub = blockIdx.x >> 4;
    const int tid = threadIdx.x;
    const int wave = tid >> 6;
    const int lane = tid & 63;
    const int m16 = lane & 15, quad = lane >> 4;
    const int r0 = sub * 4;

    __shared__ __align__(16) half_t s_enc[32 * 168];
    __shared__ __align__(16) half_t s_hid[32 * 264];

    for (int i = tid; i < 32 * 168; i += 512) {
        const int s = i / 168, k = i - s * 168;
        s_enc[i] = (half_t)((k < 150) ? enc_in[((size_t)b * 32 + s) * 150 + k] : 0.f);
    }
    __syncthreads();
    #pragma unroll
    for (int i = 0; i < 4; ++i) {
        const int ti = wave + i * 8;
        const int nt = ti & 15, mt = ti >> 4;
        f32x4 acc = (f32x4)(0.f);
        #pragma unroll
        for (int k = 0; k < 5; ++k) {
            half8 a  = *(const half8*)&s_enc[(mt * 16 + m16) * 168 + k * 32 + quad * 8];
            half8 bf = *(const half8*)&g_wf16[OFF_ENC_W1T + (nt * 16 + m16) * 160 + k * 32 + quad * 8];
            acc = MFMA(a, bf, acc);
        }
        const int j = nt * 16 + m16;
        const float bj = enc_b1[j];
        #pragma unroll
        for (int g = 0; g < 4; ++g)
            s_hid[(mt * 16 + quad * 4 + g) * 264 + j] = (half_t)fmaxf(acc[g] + bj, 0.f);
    }
    __syncthreads();
    float* h0 = g_hbuf + (size_t)b * 32 * 128;
    #pragma unroll
    for (int i = 0; i < 2; ++i) {
        const int ti = wave + i * 8;
        const int nt = ti & 7, mt = ti >> 3;
        f32x4 acc = (f32x4)(0.f);
        #pragma unroll
        for (int k = 0; k < 8; ++k) {
            half8 a  = *(const half8*)&s_hid[(mt * 16 + m16) * 264 + k * 32 + quad * 8];
            half8 bf = *(const half8*)&g_wf16[OFF_ENC_W2T + (nt * 16 + m16) * 256 + k * 32 + quad * 8];
            acc = MFMA(a, bf, acc);
        }
        if (mt == (sub >> 2) && quad == (sub & 3)) {
            const int j = nt * 16 + m16;
            const float bj = enc_b2[j];
            #pragma unroll
            for (int g = 0; g < 4; ++g)
                h0[(r0 + g) * 128 + j] = fmaxf(acc[g] + bj, 0.f);
        }
    }
}

// ---------------- fused step kernel: one block per (b, r) -------------------
// edge (P/Q + layer2 MFMA + mean, R9-validated) -> msg row r in LDS ->
// row-wise tail: node MLP (IS_DEC=0) or GRU (IS_DEC=1).
template <int IS_DEC>
__global__ void __launch_bounds__(256, 4)
step_kernel(int parity, int t,
            const float* __restrict__ b1, const float* __restrict__ b2,
            const float* __restrict__ nb1_or_ir, const float* __restrict__ nb2_or_ii,
            const float* __restrict__ b_in,
            const float* __restrict__ dec_in, float* __restrict__ out) {
    const int b = blockIdx.x >> 5;
    const int r = blockIdx.x & 31;
    const int tid = threadIdx.x;
    const int wave = tid >> 6;
    const int lane = tid & 63;
    const int m16 = lane & 15, quad = lane >> 4;

    __shared__ __align__(16) half_t s_hh[32 * 136];
    __shared__ __align__(16) half_t s_P[32 * 264];
    __shared__ __align__(16) half_t s_Qb[264];
    __shared__ __align__(16) float s_msgrow[128];
    __shared__ __align__(16) half_t s_aux[304];      // gru A row (296 used)
    __shared__ __align__(16) float s_g[512];         // gates / node hidden

    const float* hsrc = g_hbuf + (size_t)parity * 512 * 128 + (size_t)b * 32 * 128;

    // stage h[b] -> halves
    {
        const int i = tid * 16;
        const int row = i >> 7, col = i & 127;
        const float* sp = hsrc + row * 128 + col;
        half8 h0, h1;
        #pragma unroll
        for (int e = 0; e < 8; ++e) { h0[e] = (half_t)sp[e]; h1[e] = (half_t)sp[8 + e]; }
        *(half8*)&s_hh[row * 136 + col] = h0;
        *(half8*)&s_hh[row * 136 + col + 8] = h1;
    }
    __syncthreads();

    // P/Q MFMA: 48 tasks (32 P + 16 Q) over 4 waves
    {
        const half_t* w1T = g_wf16 + (IS_DEC ? OFF_DE_W1T : OFF_PE_W1T);
        const int rmt = r >> 4, rloc = r & 15;
        for (int i = 0; i < 12; ++i) {
            const int ti = wave + 4 * i;          // 0..47
            const bool isQ = ti >= 32;
            const int nt = isQ ? (ti - 32) : (ti & 15);
            const int mt = isQ ? rmt : (ti >> 4);
            const int brow = isQ ? (nt + 16) : nt;
            f32x4 acc = (f32x4)(0.f);
            #pragma unroll
            for (int k = 0; k < 4; ++k) {
                half8 a = *(const half8*)&s_hh[(mt * 16 + m16) * 136 + k * 32 + quad * 8];
                half8 bf = *(const half8*)&w1T[(brow * 16 + m16) * 128 + k * 32 + quad * 8];
                acc = MFMA(a, bf, acc);
            }
            const int j = nt * 16 + m16;
            if (!isQ) {
                #pragma unroll
                for (int g = 0; g < 4; ++g)
                    s_P[(mt * 16 + quad * 4 + g) * 264 + j] = (half_t)acc[g];
            } else {
                const float bj = b1[j];
                #pragma unroll
                for (int g = 0; g < 4; ++g)
                    if (quad * 4 + g == rloc) s_Qb[j] = (half_t)(acc[g] + bj);
            }
        }
    }
    __syncthreads();

    // edge layer-2 + relu + mean -> s_msgrow
    {
        const half_t* w2T = g_wf16 + (IS_DEC ? OFF_DE_W2T : OFF_PE_W2T);
        half8 qb[8];
        #pragma unroll
        for (int k = 0; k < 8; ++k)
            qb[k] = *(const half8*)&s_Qb[k * 32 + quad * 8];
        half8 A[2][8];
        #pragma unroll
        for (int mt = 0; mt < 2; ++mt) {
            const int s = mt * 16 + m16;
            const bool dz = (s == r);
            #pragma unroll
            for (int k = 0; k < 8; ++k) {
                half8 pv = *(const half8*)&s_P[s * 264 + k * 32 + quad * 8];
                half8 hv = relu8(pv + qb[k]);
                A[mt][k] = dz ? h8zero() : hv;
            }
        }
        #pragma unroll
        for (int ni = 0; ni < 2; ++ni) {
            const int nt = wave * 2 + ni;
            f32x4 acc0 = (f32x4)(0.f), acc1 = (f32x4)(0.f);
            #pragma unroll
            for (int k = 0; k < 8; ++k) {
                half8 bf = *(const half8*)&w2T[(nt * 16 + m16) * 256 + k * 32 + quad * 8];
                acc0 = MFMA(A[0][k], bf, acc0);
                acc1 = MFMA(A[1][k], bf, acc1);
            }
            const float b2n = b2[nt * 16 + m16];
            float pp = 0.f;
            #pragma unroll
            for (int g = 0; g < 4; ++g)
                pp += fmaxf(acc0[g] + b2n, 0.f) + fmaxf(acc1[g] + b2n, 0.f);
            pp += __shfl_xor(pp, 16);
            pp += __shfl_xor(pp, 32);
            if (quad == 0)
                s_msgrow[nt * 16 + m16] = (pp - fmaxf(b2n, 0.f)) * (1.f / 31.f);
        }
    }
    __syncthreads();

    float* h_next = g_hbuf + (size_t)(parity ^ 1) * 512 * 128 + ((size_t)b * 32 + r) * 128;

    if (!IS_DEC) {
        // ---- node MLP, row r (VALU) ----
        // layer1: hid[tid] = relu(b1n + msg . pn_w1T[tid])
        {
            const half_t* w = g_wf16 + OFF_PN_W1T + (size_t)tid * 128;
            float acc = nb1_or_ir[tid];
            #pragma unroll
            for (int k = 0; k < 128; k += 8) {
                half8 wv = *(const half8*)&w[k];
                #pragma unroll
                for (int e = 0; e < 8; ++e) acc += s_msgrow[k + e] * (float)wv[e];
            }
            s_g[tid] = fmaxf(acc, 0.f);
        }
        __syncthreads();
        // layer2: 128 outputs
        if (tid < 128) {
            const half_t* w = g_wf16 + OFF_PN_W2T + (size_t)tid * 256;
            float acc = nb2_or_ii[tid];
            #pragma unroll
            for (int k = 0; k < 256; k += 8) {
                half8 wv = *(const half8*)&w[k];
                #pragma unroll
                for (int e = 0; e < 8; ++e) acc += s_g[k + e] * (float)wv[e];
            }
            h_next[tid] = fmaxf(acc, 0.f);
        }
    } else {
        // ---- GRU, row r (VALU, dot2) ----
        for (int i = tid; i < 296; i += 256) {
            half_t v;
            if (i < 128) v = (half_t)s_msgrow[i];
            else if (i < 256) v = s_hh[r * 136 + (i - 128)];
            else if (i < 259)
                v = (half_t)dec_in[(((size_t)t * 16 + b) * 32 + r) * 3 + (i - 256)];
            else v = (half_t)0.f;
            s_aux[i] = v;
        }
        if (tid < 8) s_aux[296 + tid] = (half_t)0.f;
        __syncthreads();
        {
            const half_t* w0 = g_wf16 + OFF_WGT + (size_t)tid * 288;
            const half_t* w1 = g_wf16 + OFF_WGT + (size_t)(tid + 256) * 288;
            float acc0 = 0.f, acc1 = 0.f;
            #pragma unroll
            for (int k = 0; k < 288; k += 8) {
                half8 av = *(const half8*)&s_aux[k];
                acc0 = dot8(av, *(const half8*)&w0[k], acc0);
                acc1 = dot8(av, *(const half8*)&w1[k], acc1);
            }
            s_g[tid] = acc0;
            s_g[tid + 256] = acc1;
        }
        __syncthreads();
        if (tid < 128) {
            const int j = tid;
            const float rs = s_g[j] + nb1_or_ir[j];
            const float is = s_g[128 + j] + nb2_or_ii[j];
            const float ns = s_g[256 + j] + b_in[j];
            const float hn = s_g[384 + j];
            const float rr = 1.f / (1.f + __expf(-rs));
            const float ii = 1.f / (1.f + __expf(-is));
            const float nn = tanhf(ns + rr * hn);
            const float hold = hsrc[r * 128 + j];
            const float hnew = (1.f - ii) * nn + ii * hold;
            h_next[j] = hnew;
            const size_t grow = (size_t)b * 32 + r;
            out[(size_t)t * 512 * 128 + grow * 128 + j] = hnew;
            if (t == TSTEPS - 1)
                out[(size_t)TSTEPS * 512 * 128 + grow * 128 + j] = hnew;
        }
    }
}

extern "C" void kernel_launch(void* const* d_in, const int* in_sizes, int n_in,
                              void* d_out, int out_size, void* d_ws, size_t ws_size,
                              hipStream_t stream) {
    const float* enc_in = (const float*)d_in[0];
    const float* dec_in = (const float*)d_in[1];
    // d_in[2], d_in[3] = R, S incidence: fully-connected, not needed.
    const float* enc_w1 = (const float*)d_in[4];
    const float* enc_b1 = (const float*)d_in[5];
    const float* enc_w2 = (const float*)d_in[6];
    const float* enc_b2 = (const float*)d_in[7];
    const float* pe_w1 = (const float*)d_in[8];
    const float* pe_b1 = (const float*)d_in[9];
    const float* pe_w2 = (const float*)d_in[10];
    const float* pe_b2 = (const float*)d_in[11];
    const float* pn_w1 = (const float*)d_in[12];
    const float* pn_b1 = (const float*)d_in[13];
    const float* pn_w2 = (const float*)d_in[14];
    const float* pn_b2 = (const float*)d_in[15];
    const float* de_w1 = (const float*)d_in[16];
    const float* de_b1 = (const float*)d_in[17];
    const float* de_w2 = (const float*)d_in[18];
    const float* de_b2 = (const float*)d_in[19];
    const float* w_hr = (const float*)d_in[20];
    const float* w_hi = (const float*)d_in[21];
    const float* w_hn = (const float*)d_in[22];
    const float* w_ir = (const float*)d_in[23];
    const float* b_ir = (const float*)d_in[24];
    const float* w_ii = (const float*)d_in[25];
    const float* b_ii = (const float*)d_in[26];
    const float* w_in = (const float*)d_in[27];
    const float* b_in = (const float*)d_in[28];
    (void)d_ws; (void)ws_size; (void)in_sizes; (void)n_in;

    convert_kernel<<<(WTOTAL + 255) / 256, 256, 0, stream>>>(
        enc_w1, enc_w2, pe_w1, pe_w2, pn_w1, pn_w2, de_w1, de_w2,
        w_hr, w_hi, w_hn, w_ir, w_ii, w_in);

    encoder_kernel<<<128, 512, 0, stream>>>(enc_in, enc_b1, enc_b2);

    int p = 0;
    for (int pass = 0; pass < 2; ++pass) {
        step_kernel<0><<<512, 256, 0, stream>>>(p, 0, pe_b1, pe_b2, pn_b1, pn_b2,
                                                nullptr, nullptr, nullptr);
        p ^= 1;
    }
    float* out = (float*)d_out;
    for (int t = 0; t < TSTEPS; ++t) {
        step_kernel<1><<<512, 256, 0, stream>>>(p, t, de_b1, de_b2, b_ir, b_ii,
                                                b_in, dec_in, out);
        p ^= 1;
    }
}

// Round 11
// 1458.120 us; speedup vs baseline: 1.0157x; 1.0157x over previous
//
#include <hip/hip_runtime.h>

// GNN encoder + GRU decoder. R11 = R9 structure (2 lean launches/step; best
// measured: 770us) with the fat trimmed:
//  - h ping-pongs in BOTH f32 (GRU carry precision) and f16 (MFMA operand)
//    -> edge kernel builds A-frags straight from global f16 h: no LDS staging
//    phase, ONE __syncthreads instead of three.
//  - edge Q-projection (row r only) via VALU dot2 (256 dots K=128) instead of
//    16 MFMA tasks that discarded 15/16 lanes.
//  - gru widened to 128 blocks; WGT re-laid c=(j<<2|gate) so each 64-col slice
//    holds all 4 gates for 16 j's -> block-local epilogue.
// R10 lesson kept: never per-row-stream the 288KB gate matrix (147MB/step).

#define TSTEPS 25

typedef _Float16 half_t;
typedef __attribute__((ext_vector_type(8))) _Float16 half8;
typedef __attribute__((ext_vector_type(2))) _Float16 half2v;
typedef __attribute__((ext_vector_type(8))) short short8;
typedef __attribute__((ext_vector_type(4))) float f32x4;

#define OFF_ENC_W1T 0          // [256 j][160 k]
#define OFF_ENC_W2T 40960      // [128 j][256 k]
#define OFF_PE_W1T  73728      // [512 j][128 k]  (j<256: P, j>=256: Q)
#define OFF_PE_W2T  139264     // [128 j][256 k]
#define OFF_PN_W1T  172032     // [256 j][128 k]
#define OFF_PN_W2T  204800     // [128 j][256 k]
#define OFF_DE_W1T  237568     // [512 j][128 k]
#define OFF_DE_W2T  303104     // [128 j][256 k]
#define OFF_WGT     335872     // [512 c][288 k], c = j*4 + gate{rs,is,ns,hn}
#define WTOTAL      483328

__device__ __align__(16) half_t g_wf16[WTOTAL];
__device__ __align__(16) float  g_hf[2 * 512 * 128];    // h ping-pong, f32
__device__ __align__(16) half_t g_hh[2 * 512 * 128];    // h ping-pong, f16
__device__ __align__(16) float  g_msg[512 * 128];

__device__ __forceinline__ half8 h8zero() {
    half8 z;
    #pragma unroll
    for (int e = 0; e < 8; ++e) z[e] = (half_t)0.f;
    return z;
}
__device__ __forceinline__ half8 relu8(half8 x) {
    short8 s = *(short8*)&x;
    short8 m = s >> 15;
    s = s & ~m;
    return *(half8*)&s;
}
__device__ __forceinline__ float dot8(half8 a, half8 w, float acc) {
#if __has_builtin(__builtin_amdgcn_fdot2)
    const half2v* ap = (const half2v*)&a;
    const half2v* wp = (const half2v*)&w;
    acc = __builtin_amdgcn_fdot2(ap[0], wp[0], acc, false);
    acc = __builtin_amdgcn_fdot2(ap[1], wp[1], acc, false);
    acc = __builtin_amdgcn_fdot2(ap[2], wp[2], acc, false);
    acc = __builtin_amdgcn_fdot2(ap[3], wp[3], acc, false);
#else
    #pragma unroll
    for (int e = 0; e < 8; ++e) acc += (float)a[e] * (float)w[e];
#endif
    return acc;
}
#define MFMA(a, b, c) __builtin_amdgcn_mfma_f32_16x16x32_f16((a), (b), (c), 0, 0, 0)

// ---------------- weight conversion (once per call) ----------
__global__ void convert_kernel(const float* __restrict__ enc_w1, const float* __restrict__ enc_w2,
                               const float* __restrict__ pe_w1, const float* __restrict__ pe_w2,
                               const float* __restrict__ pn_w1, const float* __restrict__ pn_w2,
                               const float* __restrict__ de_w1, const float* __restrict__ de_w2,
                               const float* __restrict__ w_hr, const float* __restrict__ w_hi,
                               const float* __restrict__ w_hn, const float* __restrict__ w_ir,
                               const float* __restrict__ w_ii, const float* __restrict__ w_in) {
    const int idx = blockIdx.x * 256 + threadIdx.x;
    if (idx >= WTOTAL) return;
    float v = 0.f;
    if (idx < OFF_ENC_W2T) {
        int o = idx, j = o / 160, k = o - j * 160;
        v = (k < 150) ? enc_w1[k * 256 + j] : 0.f;
    } else if (idx < OFF_PE_W1T) {
        int o = idx - OFF_ENC_W2T, j = o >> 8, k = o & 255;
        v = enc_w2[k * 128 + j];
    } else if (idx < OFF_PE_W2T) {
        int o = idx - OFF_PE_W1T, j = o >> 7, k = o & 127;
        v = pe_w1[(k + ((j >= 256) ? 128 : 0)) * 256 + (j & 255)];
    } else if (idx < OFF_PN_W1T) {
        int o = idx - OFF_PE_W2T, j = o >> 8, k = o & 255;
        v = pe_w2[k * 128 + j];
    } else if (idx < OFF_PN_W2T) {
        int o = idx - OFF_PN_W1T, j = o >> 7, k = o & 127;
        v = pn_w1[k * 256 + j];
    } else if (idx < OFF_DE_W1T) {
        int o = idx - OFF_PN_W2T, j = o >> 8, k = o & 255;
        v = pn_w2[k * 128 + j];
    } else if (idx < OFF_DE_W2T) {
        int o = idx - OFF_DE_W1T, j = o >> 7, k = o & 127;
        v = de_w1[(k + ((j >= 256) ? 128 : 0)) * 256 + (j & 255)];
    } else if (idx < OFF_WGT) {
        int o = idx - OFF_DE_W2T, j = o >> 8, k = o & 255;
        v = de_w2[k * 128 + j];
    } else {
        // WGT: c = j*4 + gate
        int o = idx - OFF_WGT, c = o / 288, k = o - c * 288;
        int j = c >> 2, grp = c & 3;
        if (grp == 0)
            v = (k < 128) ? w_ir[k * 128 + j] : (k < 256) ? w_hr[(k - 128) * 128 + j]
              : (k < 259) ? w_ir[(128 + k - 256) * 128 + j] : 0.f;
        else if (grp == 1)
            v = (k < 128) ? w_ii[k * 128 + j] : (k < 256) ? w_hi[(k - 128) * 128 + j]
              : (k < 259) ? w_ii[(128 + k - 256) * 128 + j] : 0.f;
        else if (grp == 2)
            v = (k < 128) ? w_in[k * 128 + j]
              : (k >= 256 && k < 259) ? w_in[(128 + k - 256) * 128 + j] : 0.f;
        else
            v = (k >= 128 && k < 256) ? w_hn[(k - 128) * 128 + j] : 0.f;
    }
    g_wf16[idx] = (half_t)v;
}

// ---------------- encoder MLP (grid 128; writes h f32 + f16) ----------------
__global__ void __launch_bounds__(512, 2)
encoder_kernel(const float* __restrict__ enc_in,
               const float* __restrict__ enc_b1, const float* __restrict__ enc_b2) {
    const int b = blockIdx.x & 15;
    const int sub = blockIdx.x >> 4;
    const int tid = threadIdx.x;
    const int wave = tid >> 6;
    const int lane = tid & 63;
    const int m16 = lane & 15, quad = lane >> 4;
    const int r0 = sub * 4;

    __shared__ __align__(16) half_t s_enc[32 * 168];
    __shared__ __align__(16) half_t s_hid[32 * 264];

    for (int i = tid; i < 32 * 168; i += 512) {
        const int s = i / 168, k = i - s * 168;
        s_enc[i] = (half_t)((k < 150) ? enc_in[((size_t)b * 32 + s) * 150 + k] : 0.f);
    }
    __syncthreads();
    #pragma unroll
    for (int i = 0; i < 4; ++i) {
        const int ti = wave + i * 8;
        const int nt = ti & 15, mt = ti >> 4;
        f32x4 acc = (f32x4)(0.f);
        #pragma unroll
        for (int k = 0; k < 5; ++k) {
            half8 a  = *(const half8*)&s_enc[(mt * 16 + m16) * 168 + k * 32 + quad * 8];
            half8 bf = *(const half8*)&g_wf16[OFF_ENC_W1T + (nt * 16 + m16) * 160 + k * 32 + quad * 8];
            acc = MFMA(a, bf, acc);
        }
        const int j = nt * 16 + m16;
        const float bj = enc_b1[j];
        #pragma unroll
        for (int g = 0; g < 4; ++g)
            s_hid[(mt * 16 + quad * 4 + g) * 264 + j] = (half_t)fmaxf(acc[g] + bj, 0.f);
    }
    __syncthreads();
    #pragma unroll
    for (int i = 0; i < 2; ++i) {
        const int ti = wave + i * 8;
        const int nt = ti & 7, mt = ti >> 3;
        f32x4 acc = (f32x4)(0.f);
        #pragma unroll
        for (int k = 0; k < 8; ++k) {
            half8 a  = *(const half8*)&s_hid[(mt * 16 + m16) * 264 + k * 32 + quad * 8];
            half8 bf = *(const half8*)&g_wf16[OFF_ENC_W2T + (nt * 16 + m16) * 256 + k * 32 + quad * 8];
            acc = MFMA(a, bf, acc);
        }
        if (mt == (sub >> 2) && quad == (sub & 3)) {
            const int j = nt * 16 + m16;
            const float bj = enc_b2[j];
            #pragma unroll
            for (int g = 0; g < 4; ++g) {
                const float hv = fmaxf(acc[g] + bj, 0.f);
                const size_t o = ((size_t)b * 32 + r0 + g) * 128 + j;
                g_hf[o] = hv;
                g_hh[o] = (half_t)hv;
            }
        }
    }
}

// ---------------- edge kernel: one block per (b, r) -------------------------
template <int IS_DEC>
__global__ void __launch_bounds__(256, 4)
edge_kernel(int parity, const float* __restrict__ b1, const float* __restrict__ b2) {
    const int b = blockIdx.x >> 5;
    const int r = blockIdx.x & 31;
    const int tid = threadIdx.x;
    const int wave = tid >> 6;
    const int lane = tid & 63;
    const int m16 = lane & 15, quad = lane >> 4;

    __shared__ __align__(16) half_t s_P[32 * 264];
    __shared__ __align__(16) half_t s_Qb[264];

    const half_t* hh = g_hh + (size_t)parity * 512 * 128 + (size_t)b * 32 * 128;
    const half_t* w1T = g_wf16 + (IS_DEC ? OFF_DE_W1T : OFF_PE_W1T);

    // A-frags for P straight from global f16 h
    half8 a[2][4];
    #pragma unroll
    for (int mt = 0; mt < 2; ++mt)
        #pragma unroll
        for (int k = 0; k < 4; ++k)
            a[mt][k] = *(const half8*)&hh[(mt * 16 + m16) * 128 + k * 32 + quad * 8];

    // P: 32 tasks over 4 waves (8 each)
    #pragma unroll
    for (int i = 0; i < 8; ++i) {
        const int ti = wave + 4 * i;          // 0..31
        const int nt = ti & 15, mt = ti >> 4;
        f32x4 acc = (f32x4)(0.f);
        #pragma unroll
        for (int k = 0; k < 4; ++k) {
            half8 bf = *(const half8*)&w1T[(nt * 16 + m16) * 128 + k * 32 + quad * 8];
            acc = MFMA(a[mt][k], bf, acc);
        }
        const int j = nt * 16 + m16;
        #pragma unroll
        for (int g = 0; g < 4; ++g)
            s_P[(mt * 16 + quad * 4 + g) * 264 + j] = (half_t)acc[g];
    }

    // Q row r via dot2: thread j computes [h[r] . w1T_Q[j]] + b1[j]
    {
        const half_t* hr = hh + (size_t)r * 128;
        const half_t* wq = w1T + (size_t)(256 + tid) * 128;
        float acc = b1[tid];
        #pragma unroll
        for (int k = 0; k < 128; k += 8)
            acc = dot8(*(const half8*)&hr[k], *(const half8*)&wq[k], acc);
        s_Qb[tid] = (half_t)acc;
    }
    __syncthreads();

    // edge layer-2 + relu + mean -> g_msg row r
    {
        const half_t* w2T = g_wf16 + (IS_DEC ? OFF_DE_W2T : OFF_PE_W2T);
        half8 qb[8];
        #pragma unroll
        for (int k = 0; k < 8; ++k)
            qb[k] = *(const half8*)&s_Qb[k * 32 + quad * 8];
        half8 A[2][8];
        #pragma unroll
        for (int mt = 0; mt < 2; ++mt) {
            const int s = mt * 16 + m16;
            const bool dz = (s == r);
            #pragma unroll
            for (int k = 0; k < 8; ++k) {
                half8 pv = *(const half8*)&s_P[s * 264 + k * 32 + quad * 8];
                half8 hv = relu8(pv + qb[k]);
                A[mt][k] = dz ? h8zero() : hv;
            }
        }
        #pragma unroll
        for (int ni = 0; ni < 2; ++ni) {
            const int nt = wave * 2 + ni;
            f32x4 acc0 = (f32x4)(0.f), acc1 = (f32x4)(0.f);
            #pragma unroll
            for (int k = 0; k < 8; ++k) {
                half8 bf = *(const half8*)&w2T[(nt * 16 + m16) * 256 + k * 32 + quad * 8];
                acc0 = MFMA(A[0][k], bf, acc0);
                acc1 = MFMA(A[1][k], bf, acc1);
            }
            const float b2n = b2[nt * 16 + m16];
            float pp = 0.f;
            #pragma unroll
            for (int g = 0; g < 4; ++g)
                pp += fmaxf(acc0[g] + b2n, 0.f) + fmaxf(acc1[g] + b2n, 0.f);
            pp += __shfl_xor(pp, 16);
            pp += __shfl_xor(pp, 32);
            if (quad == 0)
                g_msg[((size_t)b * 32 + r) * 128 + nt * 16 + m16] =
                    (pp - fmaxf(b2n, 0.f)) * (1.f / 31.f);
        }
    }
}

// ---------------- node MLP (passing rounds): grid 32, 16 rows/block ---------
__global__ void __launch_bounds__(256, 4)
node_kernel(int parity_out, const float* __restrict__ pn_b1, const float* __restrict__ pn_b2) {
    const int mt16 = blockIdx.x;
    const int tid = threadIdx.x;
    const int wave = tid >> 6;
    const int lane = tid & 63;
    const int m16 = lane & 15, quad = lane >> 4;

    __shared__ __align__(16) half_t s_A[16 * 136];
    __shared__ __align__(16) half_t s_H[16 * 264];

    {
        const int i = tid * 8;
        const int row = i >> 7, col = i & 127;
        const float* sp = g_msg + ((size_t)mt16 * 16 + row) * 128 + col;
        half8 h0;
        #pragma unroll
        for (int e = 0; e < 8; ++e) h0[e] = (half_t)sp[e];
        *(half8*)&s_A[row * 136 + col] = h0;
    }
    __syncthreads();
    #pragma unroll
    for (int i = 0; i < 4; ++i) {
        const int nt = wave + 4 * i;
        f32x4 acc = (f32x4)(0.f);
        #pragma unroll
        for (int k = 0; k < 4; ++k) {
            half8 a = *(const half8*)&s_A[m16 * 136 + k * 32 + quad * 8];
            half8 bf = *(const half8*)&g_wf16[OFF_PN_W1T + (nt * 16 + m16) * 128 + k * 32 + quad * 8];
            acc = MFMA(a, bf, acc);
        }
        const int j = nt * 16 + m16;
        const float bj = pn_b1[j];
        #pragma unroll
        for (int g = 0; g < 4; ++g)
            s_H[(quad * 4 + g) * 264 + j] = (half_t)fmaxf(acc[g] + bj, 0.f);
    }
    __syncthreads();
    #pragma unroll
    for (int i = 0; i < 2; ++i) {
        const int nt = wave + 4 * i;
        f32x4 acc = (f32x4)(0.f);
        #pragma unroll
        for (int k = 0; k < 8; ++k) {
            half8 a = *(const half8*)&s_H[m16 * 264 + k * 32 + quad * 8];
            half8 bf = *(const half8*)&g_wf16[OFF_PN_W2T + (nt * 16 + m16) * 256 + k * 32 + quad * 8];
            acc = MFMA(a, bf, acc);
        }
        const int j = nt * 16 + m16;
        const float bj = pn_b2[j];
        #pragma unroll
        for (int g = 0; g < 4; ++g) {
            const float hv = fmaxf(acc[g] + bj, 0.f);
            const size_t o = (size_t)parity_out * 512 * 128
                           + ((size_t)mt16 * 16 + quad * 4 + g) * 128 + j;
            g_hf[o] = hv;
            g_hh[o] = (half_t)hv;
        }
    }
}

// ---------------- GRU kernel: grid 128 = (b 0..15) x (slice 0..7) -----------
// Block: 32 rows of batch b, 16 j's (x4 gates = 64 WGT cols).
__global__ void __launch_bounds__(256, 4)
gru_kernel(int parity, int t,
           const float* __restrict__ b_ir, const float* __restrict__ b_ii,
           const float* __restrict__ b_in,
           const float* __restrict__ dec_in, float* __restrict__ out) {
    const int b = blockIdx.x >> 3;
    const int slice = blockIdx.x & 7;
    const int tid = threadIdx.x;
    const int wave = tid >> 6;
    const int lane = tid & 63;
    const int m16 = lane & 15, quad = lane >> 4;
    const float* hf = g_hf + (size_t)parity * 512 * 128 + (size_t)b * 32 * 128;
    const half_t* hh = g_hh + (size_t)parity * 512 * 128 + (size_t)b * 32 * 128;

    __shared__ __align__(16) half_t s_A[32 * 296];   // [msg|h|dec|0] halves
    __shared__ float s_g[32 * 68];                   // gate pre-acts, f32

    // stage A: msg (cvt f32), h (copy f16), dec+pad
    {
        const int row = tid >> 3, c0 = (tid & 7) * 16;
        const float* mp = g_msg + ((size_t)b * 32 + row) * 128 + c0;
        half8 m0, m1;
        #pragma unroll
        for (int e = 0; e < 8; ++e) { m0[e] = (half_t)mp[e]; m1[e] = (half_t)mp[8 + e]; }
        *(half8*)&s_A[row * 296 + c0] = m0;
        *(half8*)&s_A[row * 296 + c0 + 8] = m1;
        *(half8*)&s_A[row * 296 + 128 + c0] = *(const half8*)&hh[row * 128 + c0];
        *(half8*)&s_A[row * 296 + 128 + c0 + 8] = *(const half8*)&hh[row * 128 + c0 + 8];
    }
    for (int i = tid; i < 32 * 32; i += 256) {
        const int row = i >> 5, c = i & 31;
        s_A[row * 296 + 256 + c] = (c < 3)
            ? (half_t)dec_in[(((size_t)t * 16 + b) * 32 + row) * 3 + c] : (half_t)0.f;
    }
    __syncthreads();

    // MFMA: 8 tasks (2 mt x 4 nt) / 4 waves, K=288
    #pragma unroll
    for (int i = 0; i < 2; ++i) {
        const int ti = wave + 4 * i;          // 0..7
        const int mt2 = ti >> 2, nt2 = ti & 3;
        const int c = slice * 64 + nt2 * 16 + m16;
        f32x4 acc = (f32x4)(0.f);
        #pragma unroll
        for (int k = 0; k < 9; ++k) {
            half8 a = *(const half8*)&s_A[(mt2 * 16 + m16) * 296 + k * 32 + quad * 8];
            half8 bf = *(const half8*)&g_wf16[OFF_WGT + (size_t)c * 288 + k * 32 + quad * 8];
            acc = MFMA(a, bf, acc);
        }
        #pragma unroll
        for (int g = 0; g < 4; ++g)
            s_g[(mt2 * 16 + quad * 4 + g) * 68 + nt2 * 16 + m16] = acc[g];
    }
    __syncthreads();

    // epilogue: 512 outputs / 256 thr (2 each)
    float* hf_n = g_hf + (size_t)(parity ^ 1) * 512 * 128 + (size_t)b * 32 * 128;
    half_t* hh_n = g_hh + (size_t)(parity ^ 1) * 512 * 128 + (size_t)b * 32 * 128;
    #pragma unroll
    for (int e = 0; e < 2; ++e) {
        const int idx = tid + 256 * e;
        const int row = idx >> 4, jl = idx & 15;
        const int j = slice * 16 + jl;
        const float rs = s_g[row * 68 + jl * 4 + 0] + b_ir[j];
        const float is = s_g[row * 68 + jl * 4 + 1] + b_ii[j];
        const float ns = s_g[row * 68 + jl * 4 + 2] + b_in[j];
        const float hn = s_g[row * 68 + jl * 4 + 3];
        const float rr = 1.f / (1.f + __expf(-rs));
        const float ii = 1.f / (1.f + __expf(-is));
        const float nn = tanhf(ns + rr * hn);
        const float hnew = (1.f - ii) * nn + ii * hf[row * 128 + j];
        hf_n[row * 128 + j] = hnew;
        hh_n[row * 128 + j] = (half_t)hnew;
        const size_t grow = (size_t)b * 32 + row;
        out[(size_t)t * 512 * 128 + grow * 128 + j] = hnew;
        if (t == TSTEPS - 1)
            out[(size_t)TSTEPS * 512 * 128 + grow * 128 + j] = hnew;
    }
}

extern "C" void kernel_launch(void* const* d_in, const int* in_sizes, int n_in,
                              void* d_out, int out_size, void* d_ws, size_t ws_size,
                              hipStream_t stream) {
    const float* enc_in = (const float*)d_in[0];
    const float* dec_in = (const float*)d_in[1];
    // d_in[2], d_in[3] = R, S incidence: fully-connected, not needed.
    const float* enc_w1 = (const float*)d_in[4];
    const float* enc_b1 = (const float*)d_in[5];
    const float* enc_w2 = (const float*)d_in[6];
    const float* enc_b2 = (const float*)d_in[7];
    const float* pe_w1 = (const float*)d_in[8];
    const float* pe_b1 = (const float*)d_in[9];
    const float* pe_w2 = (const float*)d_in[10];
    const float* pe_b2 = (const float*)d_in[11];
    const float* pn_w1 = (const float*)d_in[12];
    const float* pn_b1 = (const float*)d_in[13];
    const float* pn_w2 = (const float*)d_in[14];
    const float* pn_b2 = (const float*)d_in[15];
    const float* de_w1 = (const float*)d_in[16];
    const float* de_b1 = (const float*)d_in[17];
    const float* de_w2 = (const float*)d_in[18];
    const float* de_b2 = (const float*)d_in[19];
    const float* w_hr = (const float*)d_in[20];
    const float* w_hi = (const float*)d_in[21];
    const float* w_hn = (const float*)d_in[22];
    const float* w_ir = (const float*)d_in[23];
    const float* b_ir = (const float*)d_in[24];
    const float* w_ii = (const float*)d_in[25];
    const float* b_ii = (const float*)d_in[26];
    const float* w_in = (const float*)d_in[27];
    const float* b_in = (const float*)d_in[28];
    (void)d_ws; (void)ws_size; (void)in_sizes; (void)n_in;

    convert_kernel<<<(WTOTAL + 255) / 256, 256, 0, stream>>>(
        enc_w1, enc_w2, pe_w1, pe_w2, pn_w1, pn_w2, de_w1, de_w2,
        w_hr, w_hi, w_hn, w_ir, w_ii, w_in);

    encoder_kernel<<<128, 512, 0, stream>>>(enc_in, enc_b1, enc_b2);

    int p = 0;
    for (int pass = 0; pass < 2; ++pass) {
        edge_kernel<0><<<512, 256, 0, stream>>>(p, pe_b1, pe_b2);
        node_kernel<<<32, 256, 0, stream>>>(p ^ 1, pn_b1, pn_b2);
        p ^= 1;
    }
    float* out = (float*)d_out;
    for (int t = 0; t < TSTEPS; ++t) {
        edge_kernel<1><<<512, 256, 0, stream>>>(p, de_b1, de_b2);
        gru_kernel<<<128, 256, 0, stream>>>(p, t, b_ir, b_ii, b_in, dec_in, out);
        p ^= 1;
    }
}

// Round 12
// 579.473 us; speedup vs baseline: 2.5558x; 2.5163x over previous
//
#include <hip/hip_runtime.h>

// GNN encoder + GRU decoder. R12 = R9 (champion, 770us: 2 lean wide-grid
// launches/step) + FRAGMENT-MAJOR WEIGHT SWIZZLE.
// R11 post-mortem: direct-global A-frags + per-thread Q dots are uncoalesced
// (64 lines/instr) -> reverted to R9 bodies. New fix targets R9's own weight
// reads: B-frag pattern w[(nt*16+m16)*K + kk*32+quad*8] touches 16 distinct
// 64B segments per wave-load. Weights are now stored in the exact order waves
// read them: ((tile*KS+kk)*16+m16)*32 + quad*8 + e -> one contiguous 1KB
// burst per wave-load. Address permutation only; arithmetic bit-identical.

#define TSTEPS 25

typedef _Float16 half_t;
typedef __attribute__((ext_vector_type(8))) _Float16 half8;
typedef __attribute__((ext_vector_type(8))) short short8;
typedef __attribute__((ext_vector_type(4))) float f32x4;

// Regions (sizes unchanged); all stored fragment-major with KS = K/32.
#define OFF_ENC_W1T 0          // J=256 K=160 KS=5
#define OFF_ENC_W2T 40960      // J=128 K=256 KS=8
#define OFF_PE_W1T  73728      // J=512 K=128 KS=4  (j<256: P, j>=256: Q)
#define OFF_PE_W2T  139264     // J=128 K=256 KS=8
#define OFF_PN_W1T  172032     // J=256 K=128 KS=4
#define OFF_PN_W2T  204800     // J=128 K=256 KS=8
#define OFF_DE_W1T  237568     // J=512 K=128 KS=4
#define OFF_DE_W2T  303104     // J=128 K=256 KS=8
#define OFF_WGT     335872     // c=512 K=288 KS=9, c-map as R9 gru
#define WTOTAL      483328

__device__ __align__(16) half_t g_wf16[WTOTAL];
__device__ __align__(16) float g_hbuf[2 * 512 * 128];   // ping-pong h
__device__ __align__(16) float g_msg[512 * 128];

__device__ __forceinline__ half8 h8zero() {
    half8 z;
    #pragma unroll
    for (int e = 0; e < 8; ++e) z[e] = (half_t)0.f;
    return z;
}
__device__ __forceinline__ half8 relu8(half8 x) {
    short8 s = *(short8*)&x;
    short8 m = s >> 15;
    s = s & ~m;
    return *(half8*)&s;
}
#define MFMA(a, b, c) __builtin_amdgcn_mfma_f32_16x16x32_f16((a), (b), (c), 0, 0, 0)
// B-frag address in swizzled layout: tile = B-row/16, k-step kk, lane (m16,quad)
#define BFRAG(off, tile, KS, kk) ((off) + (((tile) * (KS) + (kk)) << 9) + m16 * 32 + quad * 8)

// ---------------- weight conversion into fragment-major layout --------------
__global__ void convert_kernel(const float* __restrict__ enc_w1, const float* __restrict__ enc_w2,
                               const float* __restrict__ pe_w1, const float* __restrict__ pe_w2,
                               const float* __restrict__ pn_w1, const float* __restrict__ pn_w2,
                               const float* __restrict__ de_w1, const float* __restrict__ de_w2,
                               const float* __restrict__ w_hr, const float* __restrict__ w_hi,
                               const float* __restrict__ w_hn, const float* __restrict__ w_ir,
                               const float* __restrict__ w_ii, const float* __restrict__ w_in) {
    const int idx = blockIdx.x * 256 + threadIdx.x;
    if (idx >= WTOTAL) return;
    float v = 0.f;
    if (idx < OFF_ENC_W2T) {
        int s = idx, e = s & 7, quad = (s >> 3) & 3, m16 = (s >> 5) & 15, t = s >> 9;
        int kk = t % 5, nt = t / 5;
        int j = nt * 16 + m16, k = kk * 32 + quad * 8 + e;
        v = (k < 150) ? enc_w1[k * 256 + j] : 0.f;
    } else if (idx < OFF_PE_W1T) {
        int s = idx - OFF_ENC_W2T, e = s & 7, quad = (s >> 3) & 3, m16 = (s >> 5) & 15, t = s >> 9;
        int kk = t & 7, nt = t >> 3;
        int j = nt * 16 + m16, k = kk * 32 + quad * 8 + e;
        v = enc_w2[k * 128 + j];
    } else if (idx < OFF_PE_W2T) {
        int s = idx - OFF_PE_W1T, e = s & 7, quad = (s >> 3) & 3, m16 = (s >> 5) & 15, t = s >> 9;
        int kk = t & 3, nt = t >> 2;
        int j = nt * 16 + m16, k = kk * 32 + quad * 8 + e;
        v = pe_w1[(k + ((j >= 256) ? 128 : 0)) * 256 + (j & 255)];
    } else if (idx < OFF_PN_W1T) {
        int s = idx - OFF_PE_W2T, e = s & 7, quad = (s >> 3) & 3, m16 = (s >> 5) & 15, t = s >> 9;
        int kk = t & 7, nt = t >> 3;
        int j = nt * 16 + m16, k = kk * 32 + quad * 8 + e;
        v = pe_w2[k * 128 + j];
    } else if (idx < OFF_PN_W2T) {
        int s = idx - OFF_PN_W1T, e = s & 7, quad = (s >> 3) & 3, m16 = (s >> 5) & 15, t = s >> 9;
        int kk = t & 3, nt = t >> 2;
        int j = nt * 16 + m16, k = kk * 32 + quad * 8 + e;
        v = pn_w1[k * 256 + j];
    } else if (idx < OFF_DE_W1T) {
        int s = idx - OFF_PN_W2T, e = s & 7, quad = (s >> 3) & 3, m16 = (s >> 5) & 15, t = s >> 9;
        int kk = t & 7, nt = t >> 3;
        int j = nt * 16 + m16, k = kk * 32 + quad * 8 + e;
        v = pn_w2[k * 128 + j];
    } else if (idx < OFF_DE_W2T) {
        int s = idx - OFF_DE_W1T, e = s & 7, quad = (s >> 3) & 3, m16 = (s >> 5) & 15, t = s >> 9;
        int kk = t & 3, nt = t >> 2;
        int j = nt * 16 + m16, k = kk * 32 + quad * 8 + e;
        v = de_w1[(k + ((j >= 256) ? 128 : 0)) * 256 + (j & 255)];
    } else if (idx < OFF_WGT) {
        int s = idx - OFF_DE_W2T, e = s & 7, quad = (s >> 3) & 3, m16 = (s >> 5) & 15, t = s >> 9;
        int kk = t & 7, nt = t >> 3;
        int j = nt * 16 + m16, k = kk * 32 + quad * 8 + e;
        v = de_w2[k * 128 + j];
    } else {
        int s = idx - OFF_WGT, e = s & 7, quad = (s >> 3) & 3, m16 = (s >> 5) & 15, t = s >> 9;
        int kk = t % 9, ct = t / 9;
        int c = ct * 16 + m16, k = kk * 32 + quad * 8 + e;
        int grp = (c >> 5) & 3, j = ((c >> 7) << 5) | (c & 31);
        if (grp == 0)
            v = (k < 128) ? w_ir[k * 128 + j] : (k < 256) ? w_hr[(k - 128) * 128 + j]
              : (k < 259) ? w_ir[(128 + k - 256) * 128 + j] : 0.f;
        else if (grp == 1)
            v = (k < 128) ? w_ii[k * 128 + j] : (k < 256) ? w_hi[(k - 128) * 128 + j]
              : (k < 259) ? w_ii[(128 + k - 256) * 128 + j] : 0.f;
        else if (grp == 2)
            v = (k < 128) ? w_in[k * 128 + j]
              : (k >= 256 && k < 259) ? w_in[(128 + k - 256) * 128 + j] : 0.f;
        else
            v = (k >= 128 && k < 256) ? w_hn[(k - 128) * 128 + j] : 0.f;
    }
    g_wf16[idx] = (half_t)v;
}

// ---------------- encoder MLP (grid 128; R9 body, swizzled B) ---------------
__global__ void __launch_bounds__(512, 2)
encoder_kernel(const float* __restrict__ enc_in,
               const float* __restrict__ enc_b1, const float* __restrict__ enc_b2) {
    const int b = blockIdx.x & 15;
    const int sub = blockIdx.x >> 4;
    const int tid = threadIdx.x;
    const int wave = tid >> 6;
    const int lane = tid & 63;
    const int m16 = lane & 15, quad = lane >> 4;
    const int r0 = sub * 4;

    __shared__ __align__(16) half_t s_enc[32 * 168];
    __shared__ __align__(16) half_t s_hid[32 * 264];

    for (int i = tid; i < 32 * 168; i += 512) {
        const int s = i / 168, k = i - s * 168;
        s_enc[i] = (half_t)((k < 150) ? enc_in[((size_t)b * 32 + s) * 150 + k] : 0.f);
    }
    __syncthreads();
    #pragma unroll
    for (int i = 0; i < 4; ++i) {
        const int ti = wave + i * 8;
        const int nt = ti & 15, mt = ti >> 4;
        f32x4 acc = (f32x4)(0.f);
        #pragma unroll
        for (int k = 0; k < 5; ++k) {
            half8 a  = *(const half8*)&s_enc[(mt * 16 + m16) * 168 + k * 32 + quad * 8];
            half8 bf = *(const half8*)&g_wf16[BFRAG(OFF_ENC_W1T, nt, 5, k)];
            acc = MFMA(a, bf, acc);
        }
        const int j = nt * 16 + m16;
        const float bj = enc_b1[j];
        #pragma unroll
        for (int g = 0; g < 4; ++g)
            s_hid[(mt * 16 + quad * 4 + g) * 264 + j] = (half_t)fmaxf(acc[g] + bj, 0.f);
    }
    __syncthreads();
    float* h0 = g_hbuf + (size_t)b * 32 * 128;
    #pragma unroll
    for (int i = 0; i < 2; ++i) {
        const int ti = wave + i * 8;
        const int nt = ti & 7, mt = ti >> 3;
        f32x4 acc = (f32x4)(0.f);
        #pragma unroll
        for (int k = 0; k < 8; ++k) {
            half8 a  = *(const half8*)&s_hid[(mt * 16 + m16) * 264 + k * 32 + quad * 8];
            half8 bf = *(const half8*)&g_wf16[BFRAG(OFF_ENC_W2T, nt, 8, k)];
            acc = MFMA(a, bf, acc);
        }
        if (mt == (sub >> 2) && quad == (sub & 3)) {
            const int j = nt * 16 + m16;
            const float bj = enc_b2[j];
            #pragma unroll
            for (int g = 0; g < 4; ++g)
                h0[(r0 + g) * 128 + j] = fmaxf(acc[g] + bj, 0.f);
        }
    }
}

// ---------------- edge kernel: one block per (b, r); R9 body ----------------
template <int IS_DEC>
__global__ void __launch_bounds__(256, 4)
edge_kernel(int parity, const float* __restrict__ b1, const float* __restrict__ b2) {
    const int b = blockIdx.x >> 5;
    const int r = blockIdx.x & 31;
    const int tid = threadIdx.x;
    const int wave = tid >> 6;
    const int lane = tid & 63;
    const int m16 = lane & 15, quad = lane >> 4;

    __shared__ __align__(16) half_t s_hh[32 * 136];
    __shared__ __align__(16) half_t s_P[32 * 264];
    __shared__ __align__(16) half_t s_Qb[264];

    // stage h[b] -> halves (coalesced f32 reads)
    {
        const float* hsrc = g_hbuf + (size_t)parity * 512 * 128 + (size_t)b * 32 * 128;
        const int i = tid * 16;
        const int row = i >> 7, col = i & 127;
        const float* sp = hsrc + row * 128 + col;
        half8 h0, h1;
        #pragma unroll
        for (int e = 0; e < 8; ++e) { h0[e] = (half_t)sp[e]; h1[e] = (half_t)sp[8 + e]; }
        *(half8*)&s_hh[row * 136 + col] = h0;
        *(half8*)&s_hh[row * 136 + col + 8] = h1;
    }
    __syncthreads();

    // P/Q MFMA: 48 tasks (32 P + 16 Q) over 4 waves
    {
        const int woff = IS_DEC ? OFF_DE_W1T : OFF_PE_W1T;
        const int rmt = r >> 4, rloc = r & 15;
        for (int i = 0; i < 12; ++i) {
            const int ti = wave + 4 * i;          // 0..47
            const bool isQ = ti >= 32;
            const int nt = isQ ? (ti - 32) : (ti & 15);
            const int mt = isQ ? rmt : (ti >> 4);
            const int brow = isQ ? (nt + 16) : nt;
            f32x4 acc = (f32x4)(0.f);
            #pragma unroll
            for (int k = 0; k < 4; ++k) {
                half8 a = *(const half8*)&s_hh[(mt * 16 + m16) * 136 + k * 32 + quad * 8];
                half8 bf = *(const half8*)&g_wf16[BFRAG(woff, brow, 4, k)];
                acc = MFMA(a, bf, acc);
            }
            const int j = nt * 16 + m16;
            if (!isQ) {
                #pragma unroll
                for (int g = 0; g < 4; ++g)
                    s_P[(mt * 16 + quad * 4 + g) * 264 + j] = (half_t)acc[g];
            } else {
                const float bj = b1[j];
                #pragma unroll
                for (int g = 0; g < 4; ++g)
                    if (quad * 4 + g == rloc) s_Qb[j] = (half_t)(acc[g] + bj);
            }
        }
    }
    __syncthreads();

    // edge layer-2 + relu + mean
    {
        const int woff = IS_DEC ? OFF_DE_W2T : OFF_PE_W2T;
        half8 qb[8];
        #pragma unroll
        for (int k = 0; k < 8; ++k)
            qb[k] = *(const half8*)&s_Qb[k * 32 + quad * 8];
        half8 A[2][8];
        #pragma unroll
        for (int mt = 0; mt < 2; ++mt) {
            const int s = mt * 16 + m16;
            const bool dz = (s == r);
            #pragma unroll
            for (int k = 0; k < 8; ++k) {
                half8 pv = *(const half8*)&s_P[s * 264 + k * 32 + quad * 8];
                half8 hv = relu8(pv + qb[k]);
                A[mt][k] = dz ? h8zero() : hv;
            }
        }
        #pragma unroll
        for (int ni = 0; ni < 2; ++ni) {
            const int nt = wave * 2 + ni;
            f32x4 acc0 = (f32x4)(0.f), acc1 = (f32x4)(0.f);
            #pragma unroll
            for (int k = 0; k < 8; ++k) {
                half8 bf = *(const half8*)&g_wf16[BFRAG(woff, nt, 8, k)];
                acc0 = MFMA(A[0][k], bf, acc0);
                acc1 = MFMA(A[1][k], bf, acc1);
            }
            const float b2n = b2[nt * 16 + m16];
            float pp = 0.f;
            #pragma unroll
            for (int g = 0; g < 4; ++g)
                pp += fmaxf(acc0[g] + b2n, 0.f) + fmaxf(acc1[g] + b2n, 0.f);
            pp += __shfl_xor(pp, 16);
            pp += __shfl_xor(pp, 32);
            if (quad == 0)
                g_msg[((size_t)b * 32 + r) * 128 + nt * 16 + m16] =
                    (pp - fmaxf(b2n, 0.f)) * (1.f / 31.f);
        }
    }
}

// ---------------- node MLP (passing rounds): grid 32 ------------------------
__global__ void __launch_bounds__(256, 4)
node_kernel(int parity_out, const float* __restrict__ pn_b1, const float* __restrict__ pn_b2) {
    const int mt16 = blockIdx.x;
    const int tid = threadIdx.x;
    const int wave = tid >> 6;
    const int lane = tid & 63;
    const int m16 = lane & 15, quad = lane >> 4;

    __shared__ __align__(16) half_t s_A[16 * 136];
    __shared__ __align__(16) half_t s_H[16 * 264];

    {
        const int i = tid * 8;
        const int row = i >> 7, col = i & 127;
        const float* sp = g_msg + ((size_t)mt16 * 16 + row) * 128 + col;
        half8 h0;
        #pragma unroll
        for (int e = 0; e < 8; ++e) h0[e] = (half_t)sp[e];
        *(half8*)&s_A[row * 136 + col] = h0;
    }
    __syncthreads();
    #pragma unroll
    for (int i = 0; i < 4; ++i) {
        const int nt = wave + 4 * i;
        f32x4 acc = (f32x4)(0.f);
        #pragma unroll
        for (int k = 0; k < 4; ++k) {
            half8 a = *(const half8*)&s_A[m16 * 136 + k * 32 + quad * 8];
            half8 bf = *(const half8*)&g_wf16[BFRAG(OFF_PN_W1T, nt, 4, k)];
            acc = MFMA(a, bf, acc);
        }
        const int j = nt * 16 + m16;
        const float bj = pn_b1[j];
        #pragma unroll
        for (int g = 0; g < 4; ++g)
            s_H[(quad * 4 + g) * 264 + j] = (half_t)fmaxf(acc[g] + bj, 0.f);
    }
    __syncthreads();
    float* h_next = g_hbuf + (size_t)parity_out * 512 * 128;
    #pragma unroll
    for (int i = 0; i < 2; ++i) {
        const int nt = wave + 4 * i;
        f32x4 acc = (f32x4)(0.f);
        #pragma unroll
        for (int k = 0; k < 8; ++k) {
            half8 a = *(const half8*)&s_H[m16 * 264 + k * 32 + quad * 8];
            half8 bf = *(const half8*)&g_wf16[BFRAG(OFF_PN_W2T, nt, 8, k)];
            acc = MFMA(a, bf, acc);
        }
        const int j = nt * 16 + m16;
        const float bj = pn_b2[j];
        #pragma unroll
        for (int g = 0; g < 4; ++g)
            h_next[((size_t)mt16 * 16 + quad * 4 + g) * 128 + j] = fmaxf(acc[g] + bj, 0.f);
    }
}

// ---------------- GRU kernel: grid 64 = (b 0..15) x (nt 0..3); R9 body ------
__global__ void __launch_bounds__(256, 4)
gru_kernel(int parity, int t,
           const float* __restrict__ b_ir, const float* __restrict__ b_ii,
           const float* __restrict__ b_in,
           const float* __restrict__ dec_in, float* __restrict__ out) {
    const int b = blockIdx.x >> 2;
    const int nt = blockIdx.x & 3;
    const int tid = threadIdx.x;
    const int wave = tid >> 6;
    const int lane = tid & 63;
    const int m16 = lane & 15, quad = lane >> 4;
    const float* hsrc = g_hbuf + (size_t)parity * 512 * 128 + (size_t)b * 32 * 128;

    __shared__ __align__(16) half_t s_A[32 * 296];
    __shared__ __align__(16) half_t s_g[32 * 136];

    {
        const int i = tid * 16;
        const int row = i >> 7, col = i & 127;
        const float* mp = g_msg + ((size_t)b * 32 + row) * 128 + col;
        const float* hp = hsrc + row * 128 + col;
        half8 m0, m1, h0, h1;
        #pragma unroll
        for (int e = 0; e < 8; ++e) {
            m0[e] = (half_t)mp[e]; m1[e] = (half_t)mp[8 + e];
            h0[e] = (half_t)hp[e]; h1[e] = (half_t)hp[8 + e];
        }
        *(half8*)&s_A[row * 296 + col] = m0;
        *(half8*)&s_A[row * 296 + col + 8] = m1;
        *(half8*)&s_A[row * 296 + 128 + col] = h0;
        *(half8*)&s_A[row * 296 + 128 + col + 8] = h1;
    }
    for (int i = tid; i < 32 * 32; i += 256) {
        const int row = i >> 5, c = i & 31;
        s_A[row * 296 + 256 + c] = (c < 3)
            ? (half_t)dec_in[(((size_t)t * 16 + b) * 32 + row) * 3 + c] : (half_t)0.f;
    }
    __syncthreads();

    // MFMA: 16 tasks (2 m-tiles x 8 n-sub-tiles) / 4 waves, K=288
    #pragma unroll
    for (int i = 0; i < 4; ++i) {
        const int ti = wave + 4 * i;
        const int mt2 = ti >> 3, nt2 = ti & 7;
        const int ct = nt * 8 + nt2;               // WGT tile index
        f32x4 acc = (f32x4)(0.f);
        #pragma unroll
        for (int k = 0; k < 9; ++k) {
            half8 a = *(const half8*)&s_A[(mt2 * 16 + m16) * 296 + k * 32 + quad * 8];
            half8 bf = *(const half8*)&g_wf16[BFRAG(OFF_WGT, ct, 9, k)];
            acc = MFMA(a, bf, acc);
        }
        #pragma unroll
        for (int g = 0; g < 4; ++g)
            s_g[(mt2 * 16 + quad * 4 + g) * 136 + nt2 * 16 + m16] = (half_t)acc[g];
    }
    __syncthreads();

    float* h_next = g_hbuf + (size_t)(parity ^ 1) * 512 * 128 + (size_t)b * 32 * 128;
    #pragma unroll
    for (int e = 0; e < 4; ++e) {
        const int idx = tid + 256 * e;
        const int row = idx >> 5, jl = idx & 31;
        const int j = nt * 32 + jl;
        const float rs = (float)s_g[row * 136 + jl] + b_ir[j];
        const float is = (float)s_g[row * 136 + 32 + jl] + b_ii[j];
        const float ns = (float)s_g[row * 136 + 64 + jl] + b_in[j];
        const float hn = (float)s_g[row * 136 + 96 + jl];
        const float rr = 1.f / (1.f + __expf(-rs));
        const float ii = 1.f / (1.f + __expf(-is));
        const float nn = tanhf(ns + rr * hn);
        const float hold = hsrc[row * 128 + j];
        const float hnew = (1.f - ii) * nn + ii * hold;
        h_next[row * 128 + j] = hnew;
        const size_t grow = (size_t)b * 32 + row;
        out[(size_t)t * 512 * 128 + grow * 128 + j] = hnew;
        if (t == TSTEPS - 1)
            out[(size_t)TSTEPS * 512 * 128 + grow * 128 + j] = hnew;
    }
}

extern "C" void kernel_launch(void* const* d_in, const int* in_sizes, int n_in,
                              void* d_out, int out_size, void* d_ws, size_t ws_size,
                              hipStream_t stream) {
    const float* enc_in = (const float*)d_in[0];
    const float* dec_in = (const float*)d_in[1];
    // d_in[2], d_in[3] = R, S incidence: fully-connected, not needed.
    const float* enc_w1 = (const float*)d_in[4];
    const float* enc_b1 = (const float*)d_in[5];
    const float* enc_w2 = (const float*)d_in[6];
    const float* enc_b2 = (const float*)d_in[7];
    const float* pe_w1 = (const float*)d_in[8];
    const float* pe_b1 = (const float*)d_in[9];
    const float* pe_w2 = (const float*)d_in[10];
    const float* pe_b2 = (const float*)d_in[11];
    const float* pn_w1 = (const float*)d_in[12];
    const float* pn_b1 = (const float*)d_in[13];
    const float* pn_w2 = (const float*)d_in[14];
    const float* pn_b2 = (const float*)d_in[15];
    const float* de_w1 = (const float*)d_in[16];
    const float* de_b1 = (const float*)d_in[17];
    const float* de_w2 = (const float*)d_in[18];
    const float* de_b2 = (const float*)d_in[19];
    const float* w_hr = (const float*)d_in[20];
    const float* w_hi = (const float*)d_in[21];
    const float* w_hn = (const float*)d_in[22];
    const float* w_ir = (const float*)d_in[23];
    const float* b_ir = (const float*)d_in[24];
    const float* w_ii = (const float*)d_in[25];
    const float* b_ii = (const float*)d_in[26];
    const float* w_in = (const float*)d_in[27];
    const float* b_in = (const float*)d_in[28];
    (void)d_ws; (void)ws_size; (void)in_sizes; (void)n_in;

    convert_kernel<<<(WTOTAL + 255) / 256, 256, 0, stream>>>(
        enc_w1, enc_w2, pe_w1, pe_w2, pn_w1, pn_w2, de_w1, de_w2,
        w_hr, w_hi, w_hn, w_ir, w_ii, w_in);

    encoder_kernel<<<128, 512, 0, stream>>>(enc_in, enc_b1, enc_b2);

    int p = 0;
    for (int pass = 0; pass < 2; ++pass) {
        edge_kernel<0><<<512, 256, 0, stream>>>(p, pe_b1, pe_b2);
        node_kernel<<<32, 256, 0, stream>>>(p ^ 1, pn_b1, pn_b2);
        p ^= 1;
    }
    float* out = (float*)d_out;
    for (int t = 0; t < TSTEPS; ++t) {
        edge_kernel<1><<<512, 256, 0, stream>>>(p, de_b1, de_b2);
        gru_kernel<<<64, 256, 0, stream>>>(p, t, b_ir, b_ii, b_in, dec_in, out);
        p ^= 1;
    }
}

// Round 13
// 445.356 us; speedup vs baseline: 3.3254x; 1.3011x over previous
//
#include <hip/hip_runtime.h>

// GNN encoder + GRU decoder. R13 = R12 (champion 579us: swizzled fragment-
// major weights, 2 lean launches/step) with redundancy/width tuning:
//  - edge: 256 blocks (b x r-PAIR) x 512 thr (8 waves). P redundancy 32x->16x,
//    Q/w2 tiles shared across the pair -> per-CU weight stream halves; 8 waves
//    hide L2 latency. Layer-2 A-frags built on the fly from LDS.
//  - gru: 128 blocks (m-tile split across blocks), same WGT layout.
// Weight layout, convert, encoder, node bodies: unchanged from R12.

#define TSTEPS 25

typedef _Float16 half_t;
typedef __attribute__((ext_vector_type(8))) _Float16 half8;
typedef __attribute__((ext_vector_type(8))) short short8;
typedef __attribute__((ext_vector_type(4))) float f32x4;

// Regions; all stored fragment-major with KS = K/32.
#define OFF_ENC_W1T 0          // J=256 K=160 KS=5
#define OFF_ENC_W2T 40960      // J=128 K=256 KS=8
#define OFF_PE_W1T  73728      // J=512 K=128 KS=4  (j<256: P, j>=256: Q)
#define OFF_PE_W2T  139264     // J=128 K=256 KS=8
#define OFF_PN_W1T  172032     // J=256 K=128 KS=4
#define OFF_PN_W2T  204800     // J=128 K=256 KS=8
#define OFF_DE_W1T  237568     // J=512 K=128 KS=4
#define OFF_DE_W2T  303104     // J=128 K=256 KS=8
#define OFF_WGT     335872     // c=512 K=288 KS=9
#define WTOTAL      483328

__device__ __align__(16) half_t g_wf16[WTOTAL];
__device__ __align__(16) float g_hbuf[2 * 512 * 128];   // ping-pong h
__device__ __align__(16) float g_msg[512 * 128];

__device__ __forceinline__ half8 h8zero() {
    half8 z;
    #pragma unroll
    for (int e = 0; e < 8; ++e) z[e] = (half_t)0.f;
    return z;
}
__device__ __forceinline__ half8 relu8(half8 x) {
    short8 s = *(short8*)&x;
    short8 m = s >> 15;
    s = s & ~m;
    return *(half8*)&s;
}
#define MFMA(a, b, c) __builtin_amdgcn_mfma_f32_16x16x32_f16((a), (b), (c), 0, 0, 0)
#define BFRAG(off, tile, KS, kk) ((off) + (((tile) * (KS) + (kk)) << 9) + m16 * 32 + quad * 8)

// ---------------- weight conversion into fragment-major layout (R12) --------
__global__ void convert_kernel(const float* __restrict__ enc_w1, const float* __restrict__ enc_w2,
                               const float* __restrict__ pe_w1, const float* __restrict__ pe_w2,
                               const float* __restrict__ pn_w1, const float* __restrict__ pn_w2,
                               const float* __restrict__ de_w1, const float* __restrict__ de_w2,
                               const float* __restrict__ w_hr, const float* __restrict__ w_hi,
                               const float* __restrict__ w_hn, const float* __restrict__ w_ir,
                               const float* __restrict__ w_ii, const float* __restrict__ w_in) {
    const int idx = blockIdx.x * 256 + threadIdx.x;
    if (idx >= WTOTAL) return;
    float v = 0.f;
    if (idx < OFF_ENC_W2T) {
        int s = idx, e = s & 7, quad = (s >> 3) & 3, m16 = (s >> 5) & 15, t = s >> 9;
        int kk = t % 5, nt = t / 5;
        int j = nt * 16 + m16, k = kk * 32 + quad * 8 + e;
        v = (k < 150) ? enc_w1[k * 256 + j] : 0.f;
    } else if (idx < OFF_PE_W1T) {
        int s = idx - OFF_ENC_W2T, e = s & 7, quad = (s >> 3) & 3, m16 = (s >> 5) & 15, t = s >> 9;
        int kk = t & 7, nt = t >> 3;
        int j = nt * 16 + m16, k = kk * 32 + quad * 8 + e;
        v = enc_w2[k * 128 + j];
    } else if (idx < OFF_PE_W2T) {
        int s = idx - OFF_PE_W1T, e = s & 7, quad = (s >> 3) & 3, m16 = (s >> 5) & 15, t = s >> 9;
        int kk = t & 3, nt = t >> 2;
        int j = nt * 16 + m16, k = kk * 32 + quad * 8 + e;
        v = pe_w1[(k + ((j >= 256) ? 128 : 0)) * 256 + (j & 255)];
    } else if (idx < OFF_PN_W1T) {
        int s = idx - OFF_PE_W2T, e = s & 7, quad = (s >> 3) & 3, m16 = (s >> 5) & 15, t = s >> 9;
        int kk = t & 7, nt = t >> 3;
        int j = nt * 16 + m16, k = kk * 32 + quad * 8 + e;
        v = pe_w2[k * 128 + j];
    } else if (idx < OFF_PN_W2T) {
        int s = idx - OFF_PN_W1T, e = s & 7, quad = (s >> 3) & 3, m16 = (s >> 5) & 15, t = s >> 9;
        int kk = t & 3, nt = t >> 2;
        int j = nt * 16 + m16, k = kk * 32 + quad * 8 + e;
        v = pn_w1[k * 256 + j];
    } else if (idx < OFF_DE_W1T) {
        int s = idx - OFF_PN_W2T, e = s & 7, quad = (s >> 3) & 3, m16 = (s >> 5) & 15, t = s >> 9;
        int kk = t & 7, nt = t >> 3;
        int j = nt * 16 + m16, k = kk * 32 + quad * 8 + e;
        v = pn_w2[k * 128 + j];
    } else if (idx < OFF_DE_W2T) {
        int s = idx - OFF_DE_W1T, e = s & 7, quad = (s >> 3) & 3, m16 = (s >> 5) & 15, t = s >> 9;
        int kk = t & 3, nt = t >> 2;
        int j = nt * 16 + m16, k = kk * 32 + quad * 8 + e;
        v = de_w1[(k + ((j >= 256) ? 128 : 0)) * 256 + (j & 255)];
    } else if (idx < OFF_WGT) {
        int s = idx - OFF_DE_W1T - (OFF_DE_W2T - OFF_DE_W1T), e = s & 7, quad = (s >> 3) & 3, m16 = (s >> 5) & 15, t = s >> 9;
        int kk = t & 7, nt = t >> 3;
        int j = nt * 16 + m16, k = kk * 32 + quad * 8 + e;
        v = de_w2[k * 128 + j];
    } else {
        int s = idx - OFF_WGT, e = s & 7, quad = (s >> 3) & 3, m16 = (s >> 5) & 15, t = s >> 9;
        int kk = t % 9, ct = t / 9;
        int c = ct * 16 + m16, k = kk * 32 + quad * 8 + e;
        int grp = (c >> 5) & 3, j = ((c >> 7) << 5) | (c & 31);
        if (grp == 0)
            v = (k < 128) ? w_ir[k * 128 + j] : (k < 256) ? w_hr[(k - 128) * 128 + j]
              : (k < 259) ? w_ir[(128 + k - 256) * 128 + j] : 0.f;
        else if (grp == 1)
            v = (k < 128) ? w_ii[k * 128 + j] : (k < 256) ? w_hi[(k - 128) * 128 + j]
              : (k < 259) ? w_ii[(128 + k - 256) * 128 + j] : 0.f;
        else if (grp == 2)
            v = (k < 128) ? w_in[k * 128 + j]
              : (k >= 256 && k < 259) ? w_in[(128 + k - 256) * 128 + j] : 0.f;
        else
            v = (k >= 128 && k < 256) ? w_hn[(k - 128) * 128 + j] : 0.f;
    }
    g_wf16[idx] = (half_t)v;
}

// ---------------- encoder MLP (grid 128; R12 body) --------------------------
__global__ void __launch_bounds__(512, 2)
encoder_kernel(const float* __restrict__ enc_in,
               const float* __restrict__ enc_b1, const float* __restrict__ enc_b2) {
    const int b = blockIdx.x & 15;
    const int sub = blockIdx.x >> 4;
    const int tid = threadIdx.x;
    const int wave = tid >> 6;
    const int lane = tid & 63;
    const int m16 = lane & 15, quad = lane >> 4;
    const int r0 = sub * 4;

    __shared__ __align__(16) half_t s_enc[32 * 168];
    __shared__ __align__(16) half_t s_hid[32 * 264];

    for (int i = tid; i < 32 * 168; i += 512) {
        const int s = i / 168, k = i - s * 168;
        s_enc[i] = (half_t)((k < 150) ? enc_in[((size_t)b * 32 + s) * 150 + k] : 0.f);
    }
    __syncthreads();
    #pragma unroll
    for (int i = 0; i < 4; ++i) {
        const int ti = wave + i * 8;
        const int nt = ti & 15, mt = ti >> 4;
        f32x4 acc = (f32x4)(0.f);
        #pragma unroll
        for (int k = 0; k < 5; ++k) {
            half8 a  = *(const half8*)&s_enc[(mt * 16 + m16) * 168 + k * 32 + quad * 8];
            half8 bf = *(const half8*)&g_wf16[BFRAG(OFF_ENC_W1T, nt, 5, k)];
            acc = MFMA(a, bf, acc);
        }
        const int j = nt * 16 + m16;
        const float bj = enc_b1[j];
        #pragma unroll
        for (int g = 0; g < 4; ++g)
            s_hid[(mt * 16 + quad * 4 + g) * 264 + j] = (half_t)fmaxf(acc[g] + bj, 0.f);
    }
    __syncthreads();
    float* h0 = g_hbuf + (size_t)b * 32 * 128;
    #pragma unroll
    for (int i = 0; i < 2; ++i) {
        const int ti = wave + i * 8;
        const int nt = ti & 7, mt = ti >> 3;
        f32x4 acc = (f32x4)(0.f);
        #pragma unroll
        for (int k = 0; k < 8; ++k) {
            half8 a  = *(const half8*)&s_hid[(mt * 16 + m16) * 264 + k * 32 + quad * 8];
            half8 bf = *(const half8*)&g_wf16[BFRAG(OFF_ENC_W2T, nt, 8, k)];
            acc = MFMA(a, bf, acc);
        }
        if (mt == (sub >> 2) && quad == (sub & 3)) {
            const int j = nt * 16 + m16;
            const float bj = enc_b2[j];
            #pragma unroll
            for (int g = 0; g < 4; ++g)
                h0[(r0 + g) * 128 + j] = fmaxf(acc[g] + bj, 0.f);
        }
    }
}

// ---------------- edge kernel: one block per (b, r-pair), 8 waves -----------
template <int IS_DEC>
__global__ void __launch_bounds__(512, 1)
edge_kernel(int parity, const float* __restrict__ b1, const float* __restrict__ b2) {
    const int b = blockIdx.x >> 4;
    const int rq = blockIdx.x & 15;
    const int r0 = rq * 2;
    const int tid = threadIdx.x;
    const int wave = tid >> 6;          // 0..7
    const int lane = tid & 63;
    const int m16 = lane & 15, quad = lane >> 4;

    __shared__ __align__(16) half_t s_hh[32 * 136];
    __shared__ __align__(16) half_t s_P[32 * 264];
    __shared__ __align__(16) half_t s_Qb[2 * 264];

    // stage h[b] -> halves (coalesced; 512 thr x 8 floats)
    {
        const float* hsrc = g_hbuf + (size_t)parity * 512 * 128 + (size_t)b * 32 * 128;
        const int i = tid * 8;
        const int row = i >> 7, col = i & 127;
        const float* sp = hsrc + row * 128 + col;
        half8 h0;
        #pragma unroll
        for (int e = 0; e < 8; ++e) h0[e] = (half_t)sp[e];
        *(half8*)&s_hh[row * 136 + col] = h0;
    }
    __syncthreads();

    // P (32 tasks) + Q (16 tasks, keep rows r0,r0+1) over 8 waves (6 each)
    {
        const int woff = IS_DEC ? OFF_DE_W1T : OFF_PE_W1T;
        const int rmt = r0 >> 4, rloc0 = r0 & 15;
        #pragma unroll
        for (int i = 0; i < 6; ++i) {
            const int ti = wave + 8 * i;          // 0..47
            const bool isQ = ti >= 32;
            const int nt = isQ ? (ti - 32) : (ti & 15);
            const int mt = isQ ? rmt : (ti >> 4);
            const int brow = isQ ? (nt + 16) : nt;
            f32x4 acc = (f32x4)(0.f);
            #pragma unroll
            for (int k = 0; k < 4; ++k) {
                half8 a = *(const half8*)&s_hh[(mt * 16 + m16) * 136 + k * 32 + quad * 8];
                half8 bf = *(const half8*)&g_wf16[BFRAG(woff, brow, 4, k)];
                acc = MFMA(a, bf, acc);
            }
            const int j = nt * 16 + m16;
            if (!isQ) {
                #pragma unroll
                for (int g = 0; g < 4; ++g)
                    s_P[(mt * 16 + quad * 4 + g) * 264 + j] = (half_t)acc[g];
            } else {
                const float bj = b1[j];
                #pragma unroll
                for (int g = 0; g < 4; ++g) {
                    const int rr = quad * 4 + g;
                    if (rr == rloc0)     s_Qb[j] = (half_t)(acc[g] + bj);
                    if (rr == rloc0 + 1) s_Qb[264 + j] = (half_t)(acc[g] + bj);
                }
            }
        }
    }
    __syncthreads();

    // layer-2 + relu + mean: wave w = n-tile w, both receivers, both m-tiles
    {
        const int woff2 = IS_DEC ? OFF_DE_W2T : OFF_PE_W2T;
        const int nt = wave;
        half8 qb[2][8];
        #pragma unroll
        for (int ri = 0; ri < 2; ++ri)
            #pragma unroll
            for (int k = 0; k < 8; ++k)
                qb[ri][k] = *(const half8*)&s_Qb[ri * 264 + k * 32 + quad * 8];
        f32x4 acc[2][2];
        #pragma unroll
        for (int ri = 0; ri < 2; ++ri)
            #pragma unroll
            for (int mt = 0; mt < 2; ++mt) acc[ri][mt] = (f32x4)(0.f);
        #pragma unroll
        for (int k = 0; k < 8; ++k) {
            half8 bf = *(const half8*)&g_wf16[BFRAG(woff2, nt, 8, k)];
            #pragma unroll
            for (int mt = 0; mt < 2; ++mt) {
                half8 pv = *(const half8*)&s_P[(mt * 16 + m16) * 264 + k * 32 + quad * 8];
                #pragma unroll
                for (int ri = 0; ri < 2; ++ri) {
                    half8 hv = relu8(pv + qb[ri][k]);
                    if (mt * 16 + m16 == r0 + ri) hv = h8zero();   // diag row
                    acc[ri][mt] = MFMA(hv, bf, acc[ri][mt]);
                }
            }
        }
        const float b2n = b2[nt * 16 + m16];
        #pragma unroll
        for (int ri = 0; ri < 2; ++ri) {
            float pp = 0.f;
            #pragma unroll
            for (int mt = 0; mt < 2; ++mt)
                #pragma unroll
                for (int g = 0; g < 4; ++g)
                    pp += fmaxf(acc[ri][mt][g] + b2n, 0.f);
            pp += __shfl_xor(pp, 16);
            pp += __shfl_xor(pp, 32);
            if (quad == 0)
                g_msg[((size_t)b * 32 + r0 + ri) * 128 + nt * 16 + m16] =
                    (pp - fmaxf(b2n, 0.f)) * (1.f / 31.f);
        }
    }
}

// ---------------- node MLP (passing rounds): grid 32; R12 body --------------
__global__ void __launch_bounds__(256, 4)
node_kernel(int parity_out, const float* __restrict__ pn_b1, const float* __restrict__ pn_b2) {
    const int mt16 = blockIdx.x;
    const int tid = threadIdx.x;
    const int wave = tid >> 6;
    const int lane = tid & 63;
    const int m16 = lane & 15, quad = lane >> 4;

    __shared__ __align__(16) half_t s_A[16 * 136];
    __shared__ __align__(16) half_t s_H[16 * 264];

    {
        const int i = tid * 8;
        const int row = i >> 7, col = i & 127;
        const float* sp = g_msg + ((size_t)mt16 * 16 + row) * 128 + col;
        half8 h0;
        #pragma unroll
        for (int e = 0; e < 8; ++e) h0[e] = (half_t)sp[e];
        *(half8*)&s_A[row * 136 + col] = h0;
    }
    __syncthreads();
    #pragma unroll
    for (int i = 0; i < 4; ++i) {
        const int nt = wave + 4 * i;
        f32x4 acc = (f32x4)(0.f);
        #pragma unroll
        for (int k = 0; k < 4; ++k) {
            half8 a = *(const half8*)&s_A[m16 * 136 + k * 32 + quad * 8];
            half8 bf = *(const half8*)&g_wf16[BFRAG(OFF_PN_W1T, nt, 4, k)];
            acc = MFMA(a, bf, acc);
        }
        const int j = nt * 16 + m16;
        const float bj = pn_b1[j];
        #pragma unroll
        for (int g = 0; g < 4; ++g)
            s_H[(quad * 4 + g) * 264 + j] = (half_t)fmaxf(acc[g] + bj, 0.f);
    }
    __syncthreads();
    float* h_next = g_hbuf + (size_t)parity_out * 512 * 128;
    #pragma unroll
    for (int i = 0; i < 2; ++i) {
        const int nt = wave + 4 * i;
        f32x4 acc = (f32x4)(0.f);
        #pragma unroll
        for (int k = 0; k < 8; ++k) {
            half8 a = *(const half8*)&s_H[m16 * 264 + k * 32 + quad * 8];
            half8 bf = *(const half8*)&g_wf16[BFRAG(OFF_PN_W2T, nt, 8, k)];
            acc = MFMA(a, bf, acc);
        }
        const int j = nt * 16 + m16;
        const float bj = pn_b2[j];
        #pragma unroll
        for (int g = 0; g < 4; ++g)
            h_next[((size_t)mt16 * 16 + quad * 4 + g) * 128 + j] = fmaxf(acc[g] + bj, 0.f);
    }
}

// ---------------- GRU kernel: grid 128 = (b, nt 0..3, mt2 0..1) -------------
__global__ void __launch_bounds__(256, 4)
gru_kernel(int parity, int t,
           const float* __restrict__ b_ir, const float* __restrict__ b_ii,
           const float* __restrict__ b_in,
           const float* __restrict__ dec_in, float* __restrict__ out) {
    const int b = blockIdx.x >> 3;
    const int nt = (blockIdx.x >> 1) & 3;
    const int mt2 = blockIdx.x & 1;
    const int rbase = mt2 * 16;
    const int tid = threadIdx.x;
    const int wave = tid >> 6;
    const int lane = tid & 63;
    const int m16 = lane & 15, quad = lane >> 4;
    const float* hsrc = g_hbuf + (size_t)parity * 512 * 128 + (size_t)b * 32 * 128;

    __shared__ __align__(16) half_t s_A[16 * 296];
    __shared__ __align__(16) half_t s_g[16 * 136];

    // stage A rows rbase..rbase+15: [msg|h|dec|0]
    {
        const int i = tid * 8;
        const int row = i >> 7, col = i & 127;
        const float* mp = g_msg + ((size_t)b * 32 + rbase + row) * 128 + col;
        const float* hp = hsrc + (rbase + row) * 128 + col;
        half8 m0, h0;
        #pragma unroll
        for (int e = 0; e < 8; ++e) { m0[e] = (half_t)mp[e]; h0[e] = (half_t)hp[e]; }
        *(half8*)&s_A[row * 296 + col] = m0;
        *(half8*)&s_A[row * 296 + 128 + col] = h0;
    }
    for (int i = tid; i < 16 * 32; i += 256) {
        const int row = i >> 5, c = i & 31;
        s_A[row * 296 + 256 + c] = (c < 3)
            ? (half_t)dec_in[(((size_t)t * 16 + b) * 32 + rbase + row) * 3 + c] : (half_t)0.f;
    }
    __syncthreads();

    // MFMA: 8 tasks (nt2 0..7) / 4 waves, K=288
    #pragma unroll
    for (int i = 0; i < 2; ++i) {
        const int nt2 = wave + 4 * i;
        const int ct = nt * 8 + nt2;
        f32x4 acc = (f32x4)(0.f);
        #pragma unroll
        for (int k = 0; k < 9; ++k) {
            half8 a = *(const half8*)&s_A[m16 * 296 + k * 32 + quad * 8];
            half8 bf = *(const half8*)&g_wf16[BFRAG(OFF_WGT, ct, 9, k)];
            acc = MFMA(a, bf, acc);
        }
        #pragma unroll
        for (int g = 0; g < 4; ++g)
            s_g[(quad * 4 + g) * 136 + nt2 * 16 + m16] = (half_t)acc[g];
    }
    __syncthreads();

    // epilogue: 512 outputs / 256 thr
    float* h_next = g_hbuf + (size_t)(parity ^ 1) * 512 * 128 + (size_t)b * 32 * 128;
    #pragma unroll
    for (int e = 0; e < 2; ++e) {
        const int idx = tid + 256 * e;
        const int row = idx >> 5, jl = idx & 31;
        const int j = nt * 32 + jl;
        const float rs = (float)s_g[row * 136 + jl] + b_ir[j];
        const float is = (float)s_g[row * 136 + 32 + jl] + b_ii[j];
        const float ns = (float)s_g[row * 136 + 64 + jl] + b_in[j];
        const float hn = (float)s_g[row * 136 + 96 + jl];
        const float rr = 1.f / (1.f + __expf(-rs));
        const float ii = 1.f / (1.f + __expf(-is));
        const float nn = tanhf(ns + rr * hn);
        const float hold = hsrc[(rbase + row) * 128 + j];
        const float hnew = (1.f - ii) * nn + ii * hold;
        h_next[(rbase + row) * 128 + j] = hnew;
        const size_t grow = (size_t)b * 32 + rbase + row;
        out[(size_t)t * 512 * 128 + grow * 128 + j] = hnew;
        if (t == TSTEPS - 1)
            out[(size_t)TSTEPS * 512 * 128 + grow * 128 + j] = hnew;
    }
}

extern "C" void kernel_launch(void* const* d_in, const int* in_sizes, int n_in,
                              void* d_out, int out_size, void* d_ws, size_t ws_size,
                              hipStream_t stream) {
    const float* enc_in = (const float*)d_in[0];
    const float* dec_in = (const float*)d_in[1];
    // d_in[2], d_in[3] = R, S incidence: fully-connected, not needed.
    const float* enc_w1 = (const float*)d_in[4];
    const float* enc_b1 = (const float*)d_in[5];
    const float* enc_w2 = (const float*)d_in[6];
    const float* enc_b2 = (const float*)d_in[7];
    const float* pe_w1 = (const float*)d_in[8];
    const float* pe_b1 = (const float*)d_in[9];
    const float* pe_w2 = (const float*)d_in[10];
    const float* pe_b2 = (const float*)d_in[11];
    const float* pn_w1 = (const float*)d_in[12];
    const float* pn_b1 = (const float*)d_in[13];
    const float* pn_w2 = (const float*)d_in[14];
    const float* pn_b2 = (const float*)d_in[15];
    const float* de_w1 = (const float*)d_in[16];
    const float* de_b1 = (const float*)d_in[17];
    const float* de_w2 = (const float*)d_in[18];
    const float* de_b2 = (const float*)d_in[19];
    const float* w_hr = (const float*)d_in[20];
    const float* w_hi = (const float*)d_in[21];
    const float* w_hn = (const float*)d_in[22];
    const float* w_ir = (const float*)d_in[23];
    const float* b_ir = (const float*)d_in[24];
    const float* w_ii = (const float*)d_in[25];
    const float* b_ii = (const float*)d_in[26];
    const float* w_in = (const float*)d_in[27];
    const float* b_in = (const float*)d_in[28];
    (void)d_ws; (void)ws_size; (void)in_sizes; (void)n_in;

    convert_kernel<<<(WTOTAL + 255) / 256, 256, 0, stream>>>(
        enc_w1, enc_w2, pe_w1, pe_w2, pn_w1, pn_w2, de_w1, de_w2,
        w_hr, w_hi, w_hn, w_ir, w_ii, w_in);

    encoder_kernel<<<128, 512, 0, stream>>>(enc_in, enc_b1, enc_b2);

    int p = 0;
    for (int pass = 0; pass < 2; ++pass) {
        edge_kernel<0><<<256, 512, 0, stream>>>(p, pe_b1, pe_b2);
        node_kernel<<<32, 256, 0, stream>>>(p ^ 1, pn_b1, pn_b2);
        p ^= 1;
    }
    float* out = (float*)d_out;
    for (int t = 0; t < TSTEPS; ++t) {
        edge_kernel<1><<<256, 512, 0, stream>>>(p, de_b1, de_b2);
        gru_kernel<<<128, 256, 0, stream>>>(p, t, b_ir, b_ii, b_in, dec_in, out);
        p ^= 1;
    }
}